// Round 20
// baseline (64.920 us; speedup 1.0000x reference)
//
#include <hip/hip_runtime.h>

// LocallyConnectedGC: out[bt, m] = sum_n x[bt, n] * (S*W)[n, m] + b[m]
// S = band mask, half-width 4, ring of 208 -> 9 weights per output column.
//
// R18: wave-shuffle halo, ZERO LDS in the dataflow.
//  R11-R17 proved the LDS-staged path is capped by un-hoistable band
//  re-reads (compiler remats them whenever barriers/asm clobbers exist;
//  VGPR pinned at 36 across 4 attempts) + staging/read bank conflicts.
//  New dataflow: thread owns fixed chunk c=flat%52, 16 contiguous rows.
//  Per row: ONE coalesced float4 load (own chunk); left/right neighbor
//  chunks via __shfl from lane+-1 (consecutive lanes = consecutive chunks
//  of the same row). Ring-wrap / wave-edge lanes (<=4/64, loop-invariant)
//  use masked direct loads. Band built per-thread from global W/S and
//  held in REGISTERS — no barriers, no asm memory clobbers => no remat
//  (R5 precedent: VGPR 96). R5's named A/B batch + runtime-bound pair
//  loop + sched_group_barrier(VMEM_READ) keeps loads in flight.

#define NN   208
#define NC   52      // NN/4 float4 chunks per row
#define HW   4
#define BAND 9
#define THREADS 256
#define NBLK 1664    // TT = 425984 = 52*8192 -> c invariant, 16 rows/thread
#define RPB  4       // rows per pipeline batch

typedef float vfloat4 __attribute__((ext_vector_type(4)));

struct Buf { float4 C[RPB], L[RPB], R[RPB]; };

__global__ __launch_bounds__(THREADS) void lcgc_kernel(
    const float* __restrict__ x,
    const float* __restrict__ W,
    const float* __restrict__ b,
    const float* __restrict__ S,
    float* __restrict__ out,
    int total_rows)
{
    const long long flat = (long long)blockIdx.x * THREADS + threadIdx.x;
    const long long TT   = (long long)gridDim.x * THREADS;
    const int  c    = (int)(flat % NC);
    const int  lane = threadIdx.x & 63;

    const long long rows_per_thread =
        ((long long)total_rows * NC) / TT;               // 16 (runtime)
    const long long r0 = (flat / NC) * rows_per_thread;

    // ---- Per-thread band from global W/S (registers; no barriers anywhere,
    //      so this stays hoisted — R5 precedent) ----
    float4 w4[BAND + 3], s4[BAND + 3];
    #pragma unroll
    for (int r = 0; r < BAND + 3; ++r) {
        int n = 4 * c - HW + r;
        if (n < 0) n += NN;
        else if (n >= NN) n -= NN;
        w4[r] = *reinterpret_cast<const float4*>(&W[n * NN + c * 4]);
        s4[r] = *reinterpret_cast<const float4*>(&S[n * NN + c * 4]);
    }
    float4 bnd[BAND];
    #pragma unroll
    for (int d = 0; d < BAND; ++d) {
        bnd[d].x = w4[d + 0].x * s4[d + 0].x;
        bnd[d].y = w4[d + 1].y * s4[d + 1].y;
        bnd[d].z = w4[d + 2].z * s4[d + 2].z;
        bnd[d].w = w4[d + 3].w * s4[d + 3].w;
    }
    const float4 bias4 = *reinterpret_cast<const float4*>(&b[c * 4]);

    // ---- Loop-invariant shuffle/halo descriptors ----
    // Left neighbor chunk (cols 4c-4..4c-1): chunk c-1, or c+51 ring-wrapped.
    const int slL = ((c == 0) ? (lane + 51) : (lane - 1)) & 63;
    const bool inL = (c == 0) ? (lane + 51 < 64) : (lane >= 1);
    const int c4L = (c == 0) ? (NC - 1) * 4 : (c - 1) * 4;
    // Right neighbor chunk (cols 4c+4..4c+7): chunk c+1, or chunk 0 wrapped.
    const int slR = ((c == NC - 1) ? (lane - 51) : (lane + 1)) & 63;
    const bool inR = (c == NC - 1) ? (lane >= 51) : (lane + 1 < 64);
    const int c4R = (c == NC - 1) ? 0 : (c + 1) * 4;
    const int c4  = c * 4;

    #define LOADB(Bf, row0)                                                   \
        do {                                                                  \
            _Pragma("unroll")                                                 \
            for (int j = 0; j < RPB; ++j) {                                   \
                const float* xr = x + ((row0) + j) * NN;                      \
                (Bf).C[j] = *reinterpret_cast<const float4*>(xr + c4);        \
                if (!inL)                                                     \
                    (Bf).L[j] = *reinterpret_cast<const float4*>(xr + c4L);   \
                if (!inR)                                                     \
                    (Bf).R[j] = *reinterpret_cast<const float4*>(xr + c4R);   \
            }                                                                 \
        } while (0)

    #define COMPB(Bf, row0)                                                   \
        do {                                                                  \
            _Pragma("unroll")                                                 \
            for (int j = 0; j < RPB; ++j) {                                   \
                const float4 aC = (Bf).C[j];                                  \
                float4 aL, aR;                                                \
                aL.x = __shfl(aC.x, slL); aL.y = __shfl(aC.y, slL);           \
                aL.z = __shfl(aC.z, slL); aL.w = __shfl(aC.w, slL);           \
                aR.x = __shfl(aC.x, slR); aR.y = __shfl(aC.y, slR);           \
                aR.z = __shfl(aC.z, slR); aR.w = __shfl(aC.w, slR);           \
                if (!inL) aL = (Bf).L[j];                                     \
                if (!inR) aR = (Bf).R[j];                                     \
                const float xv[12] = {aL.x, aL.y, aL.z, aL.w,                 \
                                      aC.x, aC.y, aC.z, aC.w,                 \
                                      aR.x, aR.y, aR.z, aR.w};                \
                float4 acc = bias4;                                           \
                _Pragma("unroll")                                             \
                for (int d = 0; d < BAND; ++d) {                              \
                    acc.x = fmaf(bnd[d].x, xv[0 + d], acc.x);                 \
                    acc.y = fmaf(bnd[d].y, xv[1 + d], acc.y);                 \
                    acc.z = fmaf(bnd[d].z, xv[2 + d], acc.z);                 \
                    acc.w = fmaf(bnd[d].w, xv[3 + d], acc.w);                 \
                }                                                             \
                vfloat4 av = {acc.x, acc.y, acc.z, acc.w};                    \
                __builtin_nontemporal_store(av, reinterpret_cast<vfloat4*>(   \
                    out + ((row0) + j) * NN + c4));                           \
            }                                                                 \
        } while (0)

    // ---- R5 skeleton: named A/B batches, RUNTIME pair-loop bounds ----
    const long long nb = rows_per_thread / RPB;          // 4 (runtime)
    const long long npairs = nb / 2;                     // 2 (runtime)

    long long rowA = r0;
    Buf A, B;
    LOADB(A, rowA);

    for (long long k = 0; k < npairs - 1; ++k) {
        const long long rowB = rowA + RPB;
        LOADB(B, rowB);
        __builtin_amdgcn_sched_group_barrier(0x20, 4, 0);  // cluster loads
        COMPB(A, rowA);
        const long long rowA2 = rowA + 2 * RPB;
        LOADB(A, rowA2);
        __builtin_amdgcn_sched_group_barrier(0x20, 4, 0);
        COMPB(B, rowB);
        rowA = rowA2;
    }
    {   // epilogue pair
        const long long rowB = rowA + RPB;
        LOADB(B, rowB);
        __builtin_amdgcn_sched_group_barrier(0x20, 4, 0);
        COMPB(A, rowA);
        COMPB(B, rowB);
        rowA = rowB + RPB;
    }
    // Remainder batches if nb odd (not hit at bench shape).
    for (long long rr = rowA; rr < r0 + rows_per_thread; rr += RPB) {
        LOADB(A, rr);
        COMPB(A, rr);
    }

    #undef LOADB
    #undef COMPB
}

extern "C" void kernel_launch(void* const* d_in, const int* in_sizes, int n_in,
                              void* d_out, int out_size, void* d_ws, size_t ws_size,
                              hipStream_t stream) {
    const float* x = (const float*)d_in[0];
    const float* W = (const float*)d_in[1];
    const float* b = (const float*)d_in[2];
    const float* S = (const float*)d_in[3];
    float* out = (float*)d_out;

    const int total_rows = in_sizes[0] / NN;   // 131072
    lcgc_kernel<<<dim3(NBLK), dim3(THREADS), 0, stream>>>(
        x, W, b, S, out, total_rows);
}

// Round 21
// 45.840 us; speedup vs baseline: 1.4162x; 1.4162x over previous
//
#include <hip/hip_runtime.h>

// LocallyConnectedGC: out[bt, m] = sum_n x[bt, n] * (S*W)[n, m] + b[m]
// S = band mask, half-width 4, ring of 208 -> 9 weights per output column.
//
// R19 = R12 skeleton (best: 42.7us) + band/bias in AGPRs.
//  Two proven regimes: register-band -> VGPR ~100 -> 19% occupancy,
//  latency-bound (R5/R18); LDS-band -> VGPR 36 but compiler remats 9 band
//  reads into EVERY tile (R12/R13/R14/R17) -> LDS pipe ~80% busy.
//  Escape: this kernel uses no MFMA, so AGPRs are free. Band (36 floats)
//  + bias (4) written ONCE via v_accvgpr_write_b32 (asm "=a" results are
//  NOT rematerializable); tile loop fetches via volatile v_accvgpr_read
//  right before each FMA. LDS/thread/tile: 12 -> 3 ds_read_b128.
//  Staging/sync: R12 verbatim (gload_lds 2-buffer, vmcnt(1), raw barriers).

#define NN   208
#define NC   52          // NN/4 float4 chunks per row
#define HW   4
#define BAND 9
#define TR   16          // rows per tile
#define THREADS 832      // = TR*NC threads: 13 waves
#define NBLK 512
#define TILE_F  (TR * NN)     // 3328 floats per tile

typedef float vfloat4 __attribute__((ext_vector_type(4)));

__global__ __launch_bounds__(THREADS) void lcgc_kernel(
    const float* __restrict__ x,
    const float* __restrict__ W,
    const float* __restrict__ b,
    const float* __restrict__ S,
    float* __restrict__ out,
    int total_rows)
{
    __shared__ float sX[2][TILE_F];      // 26.6 KB double-buffered x tile
    __shared__ float sBand[BAND * NN];   // 7.5 KB masked weight band

    const int tid = threadIdx.x;

    // One-time cooperative band build (coalesced over m; W/S L2-hot).
    for (int i = tid; i < BAND * NN; i += THREADS) {
        int d = i / NN;
        int m = i - d * NN;
        int n = m + d - HW;
        if (n < 0) n += NN;
        else if (n >= NN) n -= NN;
        sBand[i] = W[n * NN + m] * S[n * NN + m];
    }
    __syncthreads();

    const int c    = tid % NC;           // fixed column chunk
    const int rg   = tid / NC;           // row within tile, 0..15
    const int wave = tid >> 6;

    // ---- Band + bias into AGPRs, ONCE. asm results can't be rematted. ----
    float ag[40];                        // 36 band + 4 bias, all AGPR
    {
        const float4* band4 = reinterpret_cast<const float4*>(sBand);
        #pragma unroll
        for (int d = 0; d < BAND; ++d) {
            const float4 t = band4[d * NC + c];
            asm("v_accvgpr_write_b32 %0, %1" : "=a"(ag[4*d+0]) : "v"(t.x));
            asm("v_accvgpr_write_b32 %0, %1" : "=a"(ag[4*d+1]) : "v"(t.y));
            asm("v_accvgpr_write_b32 %0, %1" : "=a"(ag[4*d+2]) : "v"(t.z));
            asm("v_accvgpr_write_b32 %0, %1" : "=a"(ag[4*d+3]) : "v"(t.w));
        }
        const float4 bb = *reinterpret_cast<const float4*>(&b[c * 4]);
        asm("v_accvgpr_write_b32 %0, %1" : "=a"(ag[36]) : "v"(bb.x));
        asm("v_accvgpr_write_b32 %0, %1" : "=a"(ag[37]) : "v"(bb.y));
        asm("v_accvgpr_write_b32 %0, %1" : "=a"(ag[38]) : "v"(bb.z));
        asm("v_accvgpr_write_b32 %0, %1" : "=a"(ag[39]) : "v"(bb.w));
    }
    // (bias global load drains via compiler waitcnt before STAGE(0):
    //  post-loop vmem queue = stages/stores only, vmcnt counts stay exact)

    const int cm = (c == 0)      ? NC - 1 : c - 1;
    const int cp = (c == NC - 1) ? 0      : c + 1;

    const long long ntiles_total = total_rows / TR;          // 8192
    const long long nt = ntiles_total / gridDim.x;           // 16 (runtime)
    const long long t0 = (long long)blockIdx.x * nt;

    // Wave-uniform LDS staging bases (HW writes base + lane*16).
    float* const ldst0 = &sX[0][wave * 256];
    float* const ldst1 = &sX[1][wave * 256];

    #define STAGE(kt, bi)                                                     \
        do {                                                                  \
            const float* gsrc = x + (t0 + (kt)) * TILE_F + (long long)tid * 4;\
            __builtin_amdgcn_global_load_lds(                                 \
                (const __attribute__((address_space(1))) void*)(gsrc),        \
                (__attribute__((address_space(3))) void*)((bi) ? ldst1 : ldst0),\
                16, 0, 0);                                                    \
        } while (0)

    #define AREAD(dst, idx)                                                   \
        asm volatile("v_accvgpr_read_b32 %0, %1" : "=v"(dst) : "a"(ag[idx]))

    #define COMPUTE(kt, bi)                                                   \
        do {                                                                  \
            const float4* xr4 =                                               \
                reinterpret_cast<const float4*>(&sX[(bi)][rg * NN]);          \
            const float4 a = xr4[cm];                                         \
            const float4 m4 = xr4[c];                                         \
            const float4 e = xr4[cp];                                         \
            const float xv[12] = {a.x, a.y, a.z, a.w,                         \
                                  m4.x, m4.y, m4.z, m4.w,                     \
                                  e.x, e.y, e.z, e.w};                        \
            float4 acc;                                                       \
            AREAD(acc.x, 36); AREAD(acc.y, 37);                               \
            AREAD(acc.z, 38); AREAD(acc.w, 39);                               \
            _Pragma("unroll")                                                 \
            for (int d = 0; d < BAND; ++d) {                                  \
                float bx, by, bz, bw;                                         \
                AREAD(bx, 4*d+0); AREAD(by, 4*d+1);                           \
                AREAD(bz, 4*d+2); AREAD(bw, 4*d+3);                           \
                acc.x = fmaf(bx, xv[0 + d], acc.x);                           \
                acc.y = fmaf(by, xv[1 + d], acc.y);                           \
                acc.z = fmaf(bz, xv[2 + d], acc.z);                           \
                acc.w = fmaf(bw, xv[3 + d], acc.w);                           \
            }                                                                 \
            vfloat4 av = {acc.x, acc.y, acc.z, acc.w};                        \
            __builtin_nontemporal_store(av, reinterpret_cast<vfloat4*>(       \
                out + (t0 + (kt)) * TILE_F + rg * NN + c * 4));               \
        } while (0)

    // Prologue: stage tile 0 into buffer 0.
    STAGE(0, 0);

    for (long long k = 0; k < nt - 1; ++k) {
        STAGE(k + 1, (int)((k + 1) & 1));
        // Wait for tile k's loads; leaves tile k+1's staging in flight.
        asm volatile("s_waitcnt vmcnt(1)" ::: "memory");
        __builtin_amdgcn_sched_barrier(0);
        __builtin_amdgcn_s_barrier();      // all waves' tile-k data visible
        COMPUTE(k, (int)(k & 1));
        asm volatile("" ::: "memory");
        __builtin_amdgcn_s_barrier();      // reads of buf k&1 done before
                                           // iter k+1 restages it
    }
    // Epilogue: last tile, nothing left to prefetch.
    asm volatile("s_waitcnt vmcnt(0)" ::: "memory");
    __builtin_amdgcn_sched_barrier(0);
    __builtin_amdgcn_s_barrier();
    COMPUTE(nt - 1, (int)((nt - 1) & 1));

    #undef STAGE
    #undef AREAD
    #undef COMPUTE
}

extern "C" void kernel_launch(void* const* d_in, const int* in_sizes, int n_in,
                              void* d_out, int out_size, void* d_ws, size_t ws_size,
                              hipStream_t stream) {
    const float* x = (const float*)d_in[0];
    const float* W = (const float*)d_in[1];
    const float* b = (const float*)d_in[2];
    const float* S = (const float*)d_in[3];
    float* out = (float*)d_out;

    const int total_rows = in_sizes[0] / NN;   // 131072 = 8192 tiles of 16
    lcgc_kernel<<<dim3(NBLK), dim3(THREADS), 0, stream>>>(
        x, W, b, S, out, total_rows);
}